// Round 17
// baseline (89.457 us; speedup 1.0000x reference)
//
#include <hip/hip_runtime.h>
#include <math.h>

#define BB 2
#define SS 2048
#define EE 1024
#define HH 16
#define DD 64
constexpr int NROWS = BB * SS * HH;   // 65536 rows of D=64
// q pre-scale: (1/sqrt(E)) * log2(e) so attention can use exp2 directly
constexpr float SCALE_Q = 1.4426950408889634f / 32.0f;

typedef __attribute__((ext_vector_type(8))) short bf16x8;
typedef __attribute__((ext_vector_type(4))) float f32x4;
typedef __attribute__((ext_vector_type(16))) float f32x16;
typedef __attribute__((ext_vector_type(4))) unsigned u32x4;

// packed f32x2 -> bf16x2 (RNE), one VALU inst
__device__ inline unsigned cvt_pk(float lo, float hi) {
  unsigned r;
  asm("v_cvt_pk_bf16_f32 %0, %1, %2" : "=v"(r) : "v"(lo), "v"(hi));
  return r;
}

// ---------------------------------------------------------------------------
// Kernel 1: QKV projection, h-major blocks (fixed b,h; 64 s-rows, 1024
// blocks). Weights converted fp32->bf16 INLINE. Each block converts 1024
// elems of W_out. q,k via swapped operands; V written TRANSPOSED [B,H,D,S].
// ---------------------------------------------------------------------------
__global__ __launch_bounds__(256) void qkv_mfma(
    const float* __restrict__ x,
    const float* __restrict__ Wq, const float* __restrict__ Wk,
    const float* __restrict__ Wv, const float* __restrict__ Wo,
    ushort* __restrict__ qo, ushort* __restrict__ ko, ushort* __restrict__ vto,
    ushort* __restrict__ wob) {
  __shared__ __align__(16) ushort Xs[64 * 72];
  __shared__ __align__(16) ushort Ws[3][64 * 72];
  const int tid = threadIdx.x, w = tid >> 6, l = tid & 63;
  const int g = l >> 4, c = l & 15;
  const int s0 = blockIdx.x * 64, h = blockIdx.y, b = blockIdx.z;

  // W_out conversion slice: 1024 blocks x 1024 elems = 1M
  {
    const int lin = blockIdx.x + (blockIdx.y << 5) + (blockIdx.z << 9);
    const size_t base = (size_t)lin * 1024 + tid * 4;
    float4 a = *(const float4*)&Wo[base];
    uint2 r;
    r.x = cvt_pk(a.x, a.y);
    r.y = cvt_pk(a.z, a.w);
    *(uint2*)&wob[base] = r;
  }

  // stage Wq/Wk/Wv fp32 -> bf16 LDS
  for (int i = tid; i < 1536; i += 256) {
    int t = i >> 9, j = i & 511;
    int r = j >> 3, e0 = (j & 7) * 8;
    const float* W = (t == 0) ? Wq : ((t == 1) ? Wk : Wv);
    float4 va = *(const float4*)&W[r * 64 + e0];
    float4 vb = *(const float4*)&W[r * 64 + e0 + 4];
    u32x4 pk;
    pk[0] = cvt_pk(va.x, va.y);
    pk[1] = cvt_pk(va.z, va.w);
    pk[2] = cvt_pk(vb.x, vb.y);
    pk[3] = cvt_pk(vb.z, vb.w);
    *(u32x4*)&Ws[t][r * 72 + e0] = pk;
  }
  // stage X tile (64 rows, fp32 -> bf16)
  for (int i = tid; i < 1024; i += 256) {
    int r = i >> 4, c4 = (i & 15) * 4;
    float4 xv = *(const float4*)&x[(((size_t)b * SS + s0 + r) * HH + h) * DD + c4];
    uint2 pk;
    pk.x = cvt_pk(xv.x, xv.y);
    pk.y = cvt_pk(xv.z, xv.w);
    *(uint2*)&Xs[r * 72 + c4] = pk;
  }
  __syncthreads();

  // X frags: wave w owns rows w*16 + c
  bf16x8 a0 = *(bf16x8*)&Xs[(w * 16 + c) * 72 + g * 8];
  bf16x8 a1 = *(bf16x8*)&Xs[(w * 16 + c) * 72 + 32 + g * 8];

  // q and k: swapped operands -> lane holds s-row c, 4 consecutive e
#pragma unroll
  for (int t = 0; t < 2; ++t) {
    ushort* out = (t == 0) ? qo : ko;
    const float sc = (t == 0) ? SCALE_Q : 1.0f;
#pragma unroll
    for (int ct = 0; ct < 4; ++ct) {
      bf16x8 b0 = *(bf16x8*)&Ws[t][(ct * 16 + c) * 72 + g * 8];
      bf16x8 b1 = *(bf16x8*)&Ws[t][(ct * 16 + c) * 72 + 32 + g * 8];
      f32x4 acc = (f32x4){0.f, 0.f, 0.f, 0.f};
      acc = __builtin_amdgcn_mfma_f32_16x16x32_bf16(b0, a0, acc, 0, 0, 0);
      acc = __builtin_amdgcn_mfma_f32_16x16x32_bf16(b1, a1, acc, 0, 0, 0);
      uint2 pk;
      pk.x = cvt_pk(acc[0] * sc, acc[1] * sc);
      pk.y = cvt_pk(acc[2] * sc, acc[3] * sc);
      int srow = s0 + w * 16 + c;
      *(uint2*)&out[((size_t)b * SS + srow) * EE + h * DD + ct * 16 + g * 4] = pk;
    }
  }
  // v: transposed [B,H,D,S], packed 8B stores (unswapped form)
#pragma unroll
  for (int ct = 0; ct < 4; ++ct) {
    bf16x8 b0 = *(bf16x8*)&Ws[2][(ct * 16 + c) * 72 + g * 8];
    bf16x8 b1 = *(bf16x8*)&Ws[2][(ct * 16 + c) * 72 + 32 + g * 8];
    f32x4 acc = (f32x4){0.f, 0.f, 0.f, 0.f};
    acc = __builtin_amdgcn_mfma_f32_16x16x32_bf16(a0, b0, acc, 0, 0, 0);
    acc = __builtin_amdgcn_mfma_f32_16x16x32_bf16(a1, b1, acc, 0, 0, 0);
    uint2 pk;
    pk.x = cvt_pk(acc[0], acc[1]);
    pk.y = cvt_pk(acc[2], acc[3]);
    int d = ct * 16 + c;
    int srow = w * 16 + g * 4;
    *(uint2*)&vto[(((size_t)b * HH + h) * DD + d) * SS + s0 + srow] = pk;
  }
}

// ---------------------------------------------------------------------------
// Kernel 4: MFMA flash attention, 32x32x16, swapped S^T = K·Q^T, TWO-DEEP
// pipelined softmax: each barrier period runs exp(t-1) [trans] || PV(t-2)
// [MFMA] || QK(t) [MFMA] -- all mutually independent. s(t), pwv, vf carried
// in named register sets (static indexing). Nothing before the barrier
// depends on QK(t) or exp(t-1) results.
// QBLK=128 (4 waves x 32 q), KVBLK=64, dbuf, 1 barrier/iter, 512 blocks.
// ---------------------------------------------------------------------------
__global__ __launch_bounds__(256) void attn_mfma(
    const ushort* __restrict__ q, const ushort* __restrict__ k,
    const ushort* __restrict__ vt, ushort* __restrict__ o) {
  __shared__ __align__(16) ushort Ks[2][64 * 72];
  __shared__ __align__(16) ushort Vts[2][64 * 72];
  const int tid = threadIdx.x, w = tid >> 6, l = tid & 63;
  const int lq = l & 31, h2 = l >> 5;  // q-col / key-row-half
  // XCD swizzle: blockIdx%8 = XCD -> contiguous chunk of 64 works
  const int work = ((blockIdx.x & 7) << 6) | (blockIdx.x >> 3);
  const int qt = work & 15, hb = work >> 4;
  const int h = hb & 15, b = hb >> 4;
  const int q0 = qt * 128 + w * 32;

  const size_t bh_qk = (size_t)b * SS * EE + h * DD;        // + s*EE + d
  const size_t bh_vt = (size_t)b * SS * EE + h * (DD * SS); // + d*SS + s

  const int sr0 = tid >> 3;            // 0..31
  const int se0 = (tid & 7) * 8;
  // sigma: swap bits 2 and 3 of the key index (bits 0,1,4 kept)
  const int krow0 = (sr0 & 19) | ((sr0 & 4) << 1) | ((sr0 & 8) >> 1);

  // prologue: stage tile 0
  {
    bf16x8 kr0 = *(const bf16x8*)&k[bh_qk + (size_t)sr0 * EE + se0];
    bf16x8 kr1 = *(const bf16x8*)&k[bh_qk + (size_t)(sr0 + 32) * EE + se0];
    bf16x8 vr0 = *(const bf16x8*)&vt[bh_vt + (size_t)sr0 * SS + se0];
    bf16x8 vr1 = *(const bf16x8*)&vt[bh_vt + (size_t)(sr0 + 32) * SS + se0];
    *(bf16x8*)&Ks[0][krow0 * 72 + se0] = kr0;
    *(bf16x8*)&Ks[0][(krow0 + 32) * 72 + se0] = kr1;
    *(bf16x8*)&Vts[0][sr0 * 72 + se0] = vr0;
    *(bf16x8*)&Vts[0][(sr0 + 32) * 72 + se0] = vr1;
  }

  // Q B-frags: lane's q-row = q0 + lq
  bf16x8 aq[4];
#pragma unroll
  for (int db = 0; db < 4; ++db)
    aq[db] = *(const bf16x8*)&q[bh_qk + (size_t)(q0 + lq) * EE + db * 16 + h2 * 8];

  f32x16 accO[2];
  float lacc[2] = {0.f, 0.f};
#pragma unroll
  for (int ct = 0; ct < 2; ++ct)
#pragma unroll
    for (int r = 0; r < 16; ++r) accO[ct][r] = 0.f;

  // pipeline state
  f32x16 sA[2];       // s of tile t-1
  u32x4 pwvA[2][2];   // pwv of tile t-2 (PV operands)
  bf16x8 vfA[2][4];   // V frags of tile t-2
  bf16x8 vfB[2][4];   // V frags of tile t-1

  // helper macros expressed as lambdas ------------------------------------
  auto do_qk = [&](int cur, f32x16 (&sOut)[2]) {
#pragma unroll
    for (int kb = 0; kb < 2; ++kb) {
      f32x16 acc;
#pragma unroll
      for (int r = 0; r < 16; ++r) acc[r] = 0.f;
#pragma unroll
      for (int db = 0; db < 4; ++db) {
        bf16x8 ka = *(bf16x8*)&Ks[cur][(kb * 32 + lq) * 72 + db * 16 + h2 * 8];
        acc = __builtin_amdgcn_mfma_f32_32x32x16_bf16(ka, aq[db], acc, 0, 0, 0);
      }
      sOut[kb] = acc;
    }
  };
  auto do_exp = [&](const f32x16 (&sIn)[2], u32x4 (&pwvOut)[2][2]) {
#pragma unroll
    for (int kb = 0; kb < 2; ++kb)
#pragma unroll
      for (int t16 = 0; t16 < 2; ++t16)
#pragma unroll
        for (int j2 = 0; j2 < 4; ++j2) {
          float pa = __builtin_amdgcn_exp2f(sIn[kb][t16 * 8 + j2 * 2]);
          float pb = __builtin_amdgcn_exp2f(sIn[kb][t16 * 8 + j2 * 2 + 1]);
          lacc[kb] += pa + pb;
          pwvOut[kb][t16][j2] = cvt_pk(pa, pb);
        }
  };
  auto do_pv = [&](const u32x4 (&pwv)[2][2], const bf16x8 (&vf)[2][4]) {
#pragma unroll
    for (int ct = 0; ct < 2; ++ct)
#pragma unroll
      for (int kb = 0; kb < 2; ++kb)
#pragma unroll
        for (int t16 = 0; t16 < 2; ++t16)
          accO[ct] = __builtin_amdgcn_mfma_f32_32x32x16_bf16(
              vf[ct][kb * 2 + t16],
              __builtin_bit_cast(bf16x8, pwv[kb][t16]), accO[ct], 0, 0, 0);
  };
  auto do_capture = [&](int cur, bf16x8 (&vf)[2][4]) {
#pragma unroll
    for (int ct = 0; ct < 2; ++ct)
#pragma unroll
      for (int kb = 0; kb < 2; ++kb)
#pragma unroll
        for (int t16 = 0; t16 < 2; ++t16)
          vf[ct][kb * 2 + t16] = *(bf16x8*)&Vts[cur][(ct * 32 + lq) * 72 +
                                                     kb * 32 + t16 * 16 + h2 * 8];
  };

  __syncthreads();

  // ---- peel 0: QK(0) -> sA, capture vf(0) -> vfB, stage tile 1 ----
  {
    bf16x8 kr0 = *(const bf16x8*)&k[bh_qk + (size_t)(64 + sr0) * EE + se0];
    bf16x8 kr1 = *(const bf16x8*)&k[bh_qk + (size_t)(64 + sr0 + 32) * EE + se0];
    bf16x8 vr0 = *(const bf16x8*)&vt[bh_vt + 64 + (size_t)sr0 * SS + se0];
    bf16x8 vr1 = *(const bf16x8*)&vt[bh_vt + 64 + (size_t)(sr0 + 32) * SS + se0];
    do_qk(0, sA);
    do_capture(0, vfB);
    *(bf16x8*)&Ks[1][krow0 * 72 + se0] = kr0;
    *(bf16x8*)&Ks[1][(krow0 + 32) * 72 + se0] = kr1;
    *(bf16x8*)&Vts[1][sr0 * 72 + se0] = vr0;
    *(bf16x8*)&Vts[1][(sr0 + 32) * 72 + se0] = vr1;
    __syncthreads();
  }

  // ---- peel 1: exp(0) -> pwvA, QK(1) -> sA, vfA=vfB, capture vf(1) -> vfB,
  //              stage tile 2 ----
  {
    bf16x8 kr0 = *(const bf16x8*)&k[bh_qk + (size_t)(128 + sr0) * EE + se0];
    bf16x8 kr1 = *(const bf16x8*)&k[bh_qk + (size_t)(128 + sr0 + 32) * EE + se0];
    bf16x8 vr0 = *(const bf16x8*)&vt[bh_vt + 128 + (size_t)sr0 * SS + se0];
    bf16x8 vr1 = *(const bf16x8*)&vt[bh_vt + 128 + (size_t)(sr0 + 32) * SS + se0];
    do_exp(sA, pwvA);  // pwv(0)
    f32x16 sN[2];
    do_qk(1, sN);      // s(1)
#pragma unroll
    for (int ct = 0; ct < 2; ++ct)
#pragma unroll
      for (int j = 0; j < 4; ++j) vfA[ct][j] = vfB[ct][j];
    do_capture(1, vfB);  // vf(1)
#pragma unroll
    for (int kb = 0; kb < 2; ++kb) sA[kb] = sN[kb];
    *(bf16x8*)&Ks[0][krow0 * 72 + se0] = kr0;
    *(bf16x8*)&Ks[0][(krow0 + 32) * 72 + se0] = kr1;
    *(bf16x8*)&Vts[0][sr0 * 72 + se0] = vr0;
    *(bf16x8*)&Vts[0][(sr0 + 32) * 72 + se0] = vr1;
    __syncthreads();
  }

  // ---- main loop t=2..31: exp(t-1) || PV(t-2) || QK(t) ----
  for (int t = 2; t < 32; ++t) {
    const int cur = t & 1;
    const int tn = (t + 1) & 31;  // wraps at t=31 (harmless extra stage)

    bf16x8 kr0, kr1, vr0, vr1;
    {
      const size_t kb2 = bh_qk + (size_t)(tn * 64) * EE;
      kr0 = *(const bf16x8*)&k[kb2 + (size_t)sr0 * EE + se0];
      kr1 = *(const bf16x8*)&k[kb2 + (size_t)(sr0 + 32) * EE + se0];
      const size_t vb2 = bh_vt + tn * 64;
      vr0 = *(const bf16x8*)&vt[vb2 + (size_t)sr0 * SS + se0];
      vr1 = *(const bf16x8*)&vt[vb2 + (size_t)(sr0 + 32) * SS + se0];
    }

    // three independent blocks (trans / MFMA / MFMA):
    u32x4 pwvN[2][2];
    do_exp(sA, pwvN);   // exp(t-1)
    do_pv(pwvA, vfA);   // PV(t-2)
    f32x16 sN[2];
    do_qk(cur, sN);     // QK(t)

    // rotate state
#pragma unroll
    for (int ct = 0; ct < 2; ++ct)
#pragma unroll
      for (int j = 0; j < 4; ++j) vfA[ct][j] = vfB[ct][j];
    do_capture(cur, vfB);  // vf(t)
#pragma unroll
    for (int kb = 0; kb < 2; ++kb) {
      sA[kb] = sN[kb];
#pragma unroll
      for (int t16 = 0; t16 < 2; ++t16) pwvA[kb][t16] = pwvN[kb][t16];
    }

    // stage tile tn into the other buffer
    {
      const int nxt = cur ^ 1;
      *(bf16x8*)&Ks[nxt][krow0 * 72 + se0] = kr0;
      *(bf16x8*)&Ks[nxt][(krow0 + 32) * 72 + se0] = kr1;
      *(bf16x8*)&Vts[nxt][sr0 * 72 + se0] = vr0;
      *(bf16x8*)&Vts[nxt][(sr0 + 32) * 72 + se0] = vr1;
    }
    __syncthreads();
  }

  // epilogue: PV(30), then exp(31) + PV(31)
  do_pv(pwvA, vfA);
  {
    u32x4 pwvN[2][2];
    do_exp(sA, pwvN);
    do_pv(pwvN, vfB);
  }

  // normalize: wave halves hold complementary key sums for the same q
  {
    float tsum = lacc[0] + lacc[1];
    tsum += __shfl_xor(tsum, 32, 64);
    float inv = 1.f / tsum;
    size_t row = (size_t)b * SS + q0 + lq;
#pragma unroll
    for (int ct = 0; ct < 2; ++ct)
#pragma unroll
      for (int rq = 0; rq < 4; ++rq) {
        uint2 pk;
        pk.x = cvt_pk(accO[ct][rq * 4 + 0] * inv, accO[ct][rq * 4 + 1] * inv);
        pk.y = cvt_pk(accO[ct][rq * 4 + 2] * inv, accO[ct][rq * 4 + 3] * inv);
        *(uint2*)&o[row * EE + h * DD + ct * 32 + rq * 8 + h2 * 4] = pk;
      }
  }
}

// ---------------------------------------------------------------------------
// Kernel 5: output projection, 128x128 tile, 2x2 waves of 64x64 sub-tiles:
// af 8 + wf 8 ds_reads feed 16 MFMAs (1.0 reads/MFMA). W staged
// sigma-permuted per 32-block; epilogue float4 stores. Grid (32,8) = 256.
// ---------------------------------------------------------------------------
__global__ __launch_bounds__(256) void out_proj_mfma(
    const ushort* __restrict__ a, const ushort* __restrict__ wo,
    const float* __restrict__ bias, float* __restrict__ y) {
  __shared__ __align__(16) ushort As[2][128 * 72];
  __shared__ __align__(16) ushort Ws[2][128 * 72];
  const int tid = threadIdx.x, l = tid & 63;
  const int wv = tid >> 6, wm = wv >> 1, wn = wv & 1;  // 2x2 wave grid
  const int lq = l & 31, h2 = l >> 5;
  const int m0 = blockIdx.x * 128, n0 = blockIdx.y * 128;
  const int sr = tid >> 3, se = (tid & 7) * 8;
  // sigma: swap bits 2,3 of the n-row index within its 32-block
  const int krow0 = (sr & 19) | ((sr & 4) << 1) | ((sr & 8) >> 1);

  f32x16 acc[2][2];  // [mb][nb]
#pragma unroll
  for (int mb = 0; mb < 2; ++mb)
#pragma unroll
    for (int nb = 0; nb < 2; ++nb)
#pragma unroll
      for (int r = 0; r < 16; ++r) acc[mb][nb][r] = 0.f;

  // prologue: stage k0=0 into buf 0
  {
#pragma unroll
    for (int j = 0; j < 4; ++j) {
      int r = sr + j * 32;
      *(bf16x8*)&As[0][r * 72 + se] = *(const bf16x8*)&a[(size_t)(m0 + r) * EE + se];
      *(bf16x8*)&Ws[0][(j * 32 + krow0) * 72 + se] =
          *(const bf16x8*)&wo[(size_t)(n0 + r) * EE + se];
    }
  }
  __syncthreads();

  for (int t = 0; t < 16; ++t) {
    const int cur = t & 1;
    bf16x8 Arg[4], Brg[4];
    if (t < 15) {
      const int k0 = (t + 1) * 64;
#pragma unroll
      for (int j = 0; j < 4; ++j) {
        int r = sr + j * 32;
        Arg[j] = *(const bf16x8*)&a[(size_t)(m0 + r) * EE + k0 + se];
        Brg[j] = *(const bf16x8*)&wo[(size_t)(n0 + r) * EE + k0 + se];
      }
    }

    // A frags: rows wm*64 + mb*32 + lq
    bf16x8 af[2][4];
#pragma unroll
    for (int mb = 0; mb < 2; ++mb)
#pragma unroll
      for (int db = 0; db < 4; ++db)
        af[mb][db] = *(bf16x8*)&As[cur][(wm * 64 + mb * 32 + lq) * 72 +
                                        db * 16 + h2 * 8];
    // W frags (A-operand, sigma'd rows) + MFMA
#pragma unroll
    for (int nb = 0; nb < 2; ++nb)
#pragma unroll
      for (int db = 0; db < 4; ++db) {
        bf16x8 wf = *(bf16x8*)&Ws[cur][(wn * 64 + nb * 32 + lq) * 72 +
                                       db * 16 + h2 * 8];
#pragma unroll
        for (int mb = 0; mb < 2; ++mb)
          acc[mb][nb] = __builtin_amdgcn_mfma_f32_32x32x16_bf16(
              wf, af[mb][db], acc[mb][nb], 0, 0, 0);
      }

    if (t < 15) {
      const int nxt = cur ^ 1;
#pragma unroll
      for (int j = 0; j < 4; ++j) {
        int r = sr + j * 32;
        *(bf16x8*)&As[nxt][r * 72 + se] = Arg[j];
        *(bf16x8*)&Ws[nxt][(j * 32 + krow0) * 72 + se] = Brg[j];
      }
    }
    __syncthreads();
  }

  // epilogue: lane owns m-row m0+wm*64+mb*32+lq;
  // regs t16*8+j -> n = n0 + wn*64 + nb*32 + t16*16 + h2*8 + j
#pragma unroll
  for (int mb = 0; mb < 2; ++mb) {
    const size_t row = (size_t)(m0 + wm * 64 + mb * 32 + lq) * EE;
#pragma unroll
    for (int nb = 0; nb < 2; ++nb)
#pragma unroll
      for (int t16 = 0; t16 < 2; ++t16) {
        const int nbase = n0 + wn * 64 + nb * 32 + t16 * 16 + h2 * 8;
        float4 bv0 = *(const float4*)&bias[nbase];
        float4 bv1 = *(const float4*)&bias[nbase + 4];
        float4 o0 = {acc[mb][nb][t16 * 8 + 0] + bv0.x,
                     acc[mb][nb][t16 * 8 + 1] + bv0.y,
                     acc[mb][nb][t16 * 8 + 2] + bv0.z,
                     acc[mb][nb][t16 * 8 + 3] + bv0.w};
        float4 o1 = {acc[mb][nb][t16 * 8 + 4] + bv1.x,
                     acc[mb][nb][t16 * 8 + 5] + bv1.y,
                     acc[mb][nb][t16 * 8 + 6] + bv1.z,
                     acc[mb][nb][t16 * 8 + 7] + bv1.w};
        *(float4*)&y[row + nbase] = o0;
        *(float4*)&y[row + nbase + 4] = o1;
      }
  }
}

// ---------------------------------------------------------------------------
extern "C" void kernel_launch(void* const* d_in, const int* in_sizes, int n_in,
                              void* d_out, int out_size, void* d_ws,
                              size_t ws_size, hipStream_t stream) {
  const float* x = (const float*)d_in[0];
  const float* Wq = (const float*)d_in[1];
  const float* Wk = (const float*)d_in[2];
  const float* Wv = (const float*)d_in[3];
  const float* Wo = (const float*)d_in[4];
  const float* bo = (const float*)d_in[5];
  float* out = (float*)d_out;

  const size_t per = (size_t)NROWS * 64;  // 4,194,304 elems
  ushort* qb = (ushort*)d_ws;                       //  8 MB
  ushort* kb = qb + per;                            //  8 MB
  ushort* vtb = kb + per;                           //  8 MB
  ushort* aob = vtb + per;                          //  8 MB
  ushort* wob = aob + per;                          //  2 MB

  qkv_mfma<<<dim3(32, 16, 2), 256, 0, stream>>>(x, Wq, Wk, Wv, Wo,
                                                qb, kb, vtb, wob);
  attn_mfma<<<512, 256, 0, stream>>>(qb, kb, vtb, aob);
  out_proj_mfma<<<dim3(32, 8), 256, 0, stream>>>(aob, wob, bo, out);
}

// Round 18
// 79.147 us; speedup vs baseline: 1.1303x; 1.1303x over previous
//
#include <hip/hip_runtime.h>
#include <math.h>

#define BB 2
#define SS 2048
#define EE 1024
#define HH 16
#define DD 64
constexpr int NROWS = BB * SS * HH;   // 65536 rows of D=64
// q pre-scale: (1/sqrt(E)) * log2(e) so attention can use exp2 directly
constexpr float SCALE_Q = 1.4426950408889634f / 32.0f;

typedef __attribute__((ext_vector_type(8))) short bf16x8;
typedef __attribute__((ext_vector_type(4))) float f32x4;
typedef __attribute__((ext_vector_type(16))) float f32x16;
typedef __attribute__((ext_vector_type(4))) unsigned u32x4;

// packed f32x2 -> bf16x2 (RNE), one VALU inst
__device__ inline unsigned cvt_pk(float lo, float hi) {
  unsigned r;
  asm("v_cvt_pk_bf16_f32 %0, %1, %2" : "=v"(r) : "v"(lo), "v"(hi));
  return r;
}

// ---------------------------------------------------------------------------
// Kernel 1: QKV projection, h-major blocks (fixed b,h; 64 s-rows, 1024
// blocks). Weights converted fp32->bf16 INLINE. Each block converts 1024
// elems of W_out. q,k via swapped operands; V written TRANSPOSED [B,H,D,S].
// ---------------------------------------------------------------------------
__global__ __launch_bounds__(256) void qkv_mfma(
    const float* __restrict__ x,
    const float* __restrict__ Wq, const float* __restrict__ Wk,
    const float* __restrict__ Wv, const float* __restrict__ Wo,
    ushort* __restrict__ qo, ushort* __restrict__ ko, ushort* __restrict__ vto,
    ushort* __restrict__ wob) {
  __shared__ __align__(16) ushort Xs[64 * 72];
  __shared__ __align__(16) ushort Ws[3][64 * 72];
  const int tid = threadIdx.x, w = tid >> 6, l = tid & 63;
  const int g = l >> 4, c = l & 15;
  const int s0 = blockIdx.x * 64, h = blockIdx.y, b = blockIdx.z;

  // W_out conversion slice: 1024 blocks x 1024 elems = 1M
  {
    const int lin = blockIdx.x + (blockIdx.y << 5) + (blockIdx.z << 9);
    const size_t base = (size_t)lin * 1024 + tid * 4;
    float4 a = *(const float4*)&Wo[base];
    uint2 r;
    r.x = cvt_pk(a.x, a.y);
    r.y = cvt_pk(a.z, a.w);
    *(uint2*)&wob[base] = r;
  }

  // stage Wq/Wk/Wv fp32 -> bf16 LDS
  for (int i = tid; i < 1536; i += 256) {
    int t = i >> 9, j = i & 511;
    int r = j >> 3, e0 = (j & 7) * 8;
    const float* W = (t == 0) ? Wq : ((t == 1) ? Wk : Wv);
    float4 va = *(const float4*)&W[r * 64 + e0];
    float4 vb = *(const float4*)&W[r * 64 + e0 + 4];
    u32x4 pk;
    pk[0] = cvt_pk(va.x, va.y);
    pk[1] = cvt_pk(va.z, va.w);
    pk[2] = cvt_pk(vb.x, vb.y);
    pk[3] = cvt_pk(vb.z, vb.w);
    *(u32x4*)&Ws[t][r * 72 + e0] = pk;
  }
  // stage X tile (64 rows, fp32 -> bf16)
  for (int i = tid; i < 1024; i += 256) {
    int r = i >> 4, c4 = (i & 15) * 4;
    float4 xv = *(const float4*)&x[(((size_t)b * SS + s0 + r) * HH + h) * DD + c4];
    uint2 pk;
    pk.x = cvt_pk(xv.x, xv.y);
    pk.y = cvt_pk(xv.z, xv.w);
    *(uint2*)&Xs[r * 72 + c4] = pk;
  }
  __syncthreads();

  // X frags: wave w owns rows w*16 + c
  bf16x8 a0 = *(bf16x8*)&Xs[(w * 16 + c) * 72 + g * 8];
  bf16x8 a1 = *(bf16x8*)&Xs[(w * 16 + c) * 72 + 32 + g * 8];

  // q and k: swapped operands -> lane holds s-row c, 4 consecutive e
#pragma unroll
  for (int t = 0; t < 2; ++t) {
    ushort* out = (t == 0) ? qo : ko;
    const float sc = (t == 0) ? SCALE_Q : 1.0f;
#pragma unroll
    for (int ct = 0; ct < 4; ++ct) {
      bf16x8 b0 = *(bf16x8*)&Ws[t][(ct * 16 + c) * 72 + g * 8];
      bf16x8 b1 = *(bf16x8*)&Ws[t][(ct * 16 + c) * 72 + 32 + g * 8];
      f32x4 acc = (f32x4){0.f, 0.f, 0.f, 0.f};
      acc = __builtin_amdgcn_mfma_f32_16x16x32_bf16(b0, a0, acc, 0, 0, 0);
      acc = __builtin_amdgcn_mfma_f32_16x16x32_bf16(b1, a1, acc, 0, 0, 0);
      uint2 pk;
      pk.x = cvt_pk(acc[0] * sc, acc[1] * sc);
      pk.y = cvt_pk(acc[2] * sc, acc[3] * sc);
      int srow = s0 + w * 16 + c;
      *(uint2*)&out[((size_t)b * SS + srow) * EE + h * DD + ct * 16 + g * 4] = pk;
    }
  }
  // v: transposed [B,H,D,S], packed 8B stores (unswapped form)
#pragma unroll
  for (int ct = 0; ct < 4; ++ct) {
    bf16x8 b0 = *(bf16x8*)&Ws[2][(ct * 16 + c) * 72 + g * 8];
    bf16x8 b1 = *(bf16x8*)&Ws[2][(ct * 16 + c) * 72 + 32 + g * 8];
    f32x4 acc = (f32x4){0.f, 0.f, 0.f, 0.f};
    acc = __builtin_amdgcn_mfma_f32_16x16x32_bf16(a0, b0, acc, 0, 0, 0);
    acc = __builtin_amdgcn_mfma_f32_16x16x32_bf16(a1, b1, acc, 0, 0, 0);
    uint2 pk;
    pk.x = cvt_pk(acc[0], acc[1]);
    pk.y = cvt_pk(acc[2], acc[3]);
    int d = ct * 16 + c;
    int srow = w * 16 + g * 4;
    *(uint2*)&vto[(((size_t)b * HH + h) * DD + d) * SS + s0 + srow] = pk;
  }
}

// ---------------------------------------------------------------------------
// Kernel 4: MFMA flash attention (proven r12 version: 32x32x16, swapped
// S^T = K·Q^T, software-pipelined softmax, PV-first, KVBLK=64, 1 barrier/it).
// ---------------------------------------------------------------------------
__global__ __launch_bounds__(256) void attn_mfma(
    const ushort* __restrict__ q, const ushort* __restrict__ k,
    const ushort* __restrict__ vt, ushort* __restrict__ o) {
  __shared__ __align__(16) ushort Ks[2][64 * 72];
  __shared__ __align__(16) ushort Vts[2][64 * 72];
  const int tid = threadIdx.x, w = tid >> 6, l = tid & 63;
  const int lq = l & 31, h2 = l >> 5;  // q-col / key-row-half
  // XCD swizzle: blockIdx%8 = XCD -> contiguous chunk of 64 works
  const int work = ((blockIdx.x & 7) << 6) | (blockIdx.x >> 3);
  const int qt = work & 15, hb = work >> 4;
  const int h = hb & 15, b = hb >> 4;
  const int q0 = qt * 128 + w * 32;

  const size_t bh_qk = (size_t)b * SS * EE + h * DD;        // + s*EE + d
  const size_t bh_vt = (size_t)b * SS * EE + h * (DD * SS); // + d*SS + s

  const int sr0 = tid >> 3;            // 0..31
  const int se0 = (tid & 7) * 8;
  // sigma: swap bits 2 and 3 of the key index (bits 0,1,4 kept)
  const int krow0 = (sr0 & 19) | ((sr0 & 4) << 1) | ((sr0 & 8) >> 1);

  // prologue: stage tile 0
  {
    bf16x8 kr0 = *(const bf16x8*)&k[bh_qk + (size_t)sr0 * EE + se0];
    bf16x8 kr1 = *(const bf16x8*)&k[bh_qk + (size_t)(sr0 + 32) * EE + se0];
    bf16x8 vr0 = *(const bf16x8*)&vt[bh_vt + (size_t)sr0 * SS + se0];
    bf16x8 vr1 = *(const bf16x8*)&vt[bh_vt + (size_t)(sr0 + 32) * SS + se0];
    *(bf16x8*)&Ks[0][krow0 * 72 + se0] = kr0;
    *(bf16x8*)&Ks[0][(krow0 + 32) * 72 + se0] = kr1;
    *(bf16x8*)&Vts[0][sr0 * 72 + se0] = vr0;
    *(bf16x8*)&Vts[0][(sr0 + 32) * 72 + se0] = vr1;
  }

  // Q B-frags: lane's q-row = q0 + lq
  bf16x8 aq[4];
#pragma unroll
  for (int db = 0; db < 4; ++db)
    aq[db] = *(const bf16x8*)&q[bh_qk + (size_t)(q0 + lq) * EE + db * 16 + h2 * 8];

  f32x16 accO[2];
  float lacc[2] = {0.f, 0.f};
#pragma unroll
  for (int ct = 0; ct < 2; ++ct)
#pragma unroll
    for (int r = 0; r < 16; ++r) accO[ct][r] = 0.f;

  u32x4 pwvP[2][2];   // previous tile's P (PV operands)
  bf16x8 vfP[2][4];   // previous tile's V frags [ct][kb*2+t16]

  __syncthreads();

  // ---- iter 0 (peeled: QK+exp only, capture V frags; no PV) ----
  {
    bf16x8 kr0 = *(const bf16x8*)&k[bh_qk + (size_t)(64 + sr0) * EE + se0];
    bf16x8 kr1 = *(const bf16x8*)&k[bh_qk + (size_t)(64 + sr0 + 32) * EE + se0];
    bf16x8 vr0 = *(const bf16x8*)&vt[bh_vt + 64 + (size_t)sr0 * SS + se0];
    bf16x8 vr1 = *(const bf16x8*)&vt[bh_vt + 64 + (size_t)(sr0 + 32) * SS + se0];

    f32x16 s[2];
#pragma unroll
    for (int kb = 0; kb < 2; ++kb) {
      f32x16 acc;
#pragma unroll
      for (int r = 0; r < 16; ++r) acc[r] = 0.f;
#pragma unroll
      for (int db = 0; db < 4; ++db) {
        bf16x8 ka = *(bf16x8*)&Ks[0][(kb * 32 + lq) * 72 + db * 16 + h2 * 8];
        acc = __builtin_amdgcn_mfma_f32_32x32x16_bf16(ka, aq[db], acc, 0, 0, 0);
      }
      s[kb] = acc;
    }
#pragma unroll
    for (int kb = 0; kb < 2; ++kb)
#pragma unroll
      for (int t16 = 0; t16 < 2; ++t16)
#pragma unroll
        for (int j2 = 0; j2 < 4; ++j2) {
          float pa = __builtin_amdgcn_exp2f(s[kb][t16 * 8 + j2 * 2]);
          float pb = __builtin_amdgcn_exp2f(s[kb][t16 * 8 + j2 * 2 + 1]);
          lacc[kb] += pa + pb;
          pwvP[kb][t16][j2] = cvt_pk(pa, pb);
        }
#pragma unroll
    for (int ct = 0; ct < 2; ++ct)
#pragma unroll
      for (int kb = 0; kb < 2; ++kb)
#pragma unroll
        for (int t16 = 0; t16 < 2; ++t16)
          vfP[ct][kb * 2 + t16] = *(bf16x8*)&Vts[0][(ct * 32 + lq) * 72 +
                                                    kb * 32 + t16 * 16 + h2 * 8];
    *(bf16x8*)&Ks[1][krow0 * 72 + se0] = kr0;
    *(bf16x8*)&Ks[1][(krow0 + 32) * 72 + se0] = kr1;
    *(bf16x8*)&Vts[1][sr0 * 72 + se0] = vr0;
    *(bf16x8*)&Vts[1][(sr0 + 32) * 72 + se0] = vr1;
    __syncthreads();
  }

  // ---- main loop: PV(t-1) FIRST (reg-only), then QK(t), exp(t) ----
  for (int t = 1; t < 32; ++t) {
    const int cur = t & 1;
    const int tn = (t + 1) & 31;  // wraps to 0 at t=31 (harmless extra stage)

    bf16x8 kr0, kr1, vr0, vr1;
    {
      const size_t kb2 = bh_qk + (size_t)(tn * 64) * EE;
      kr0 = *(const bf16x8*)&k[kb2 + (size_t)sr0 * EE + se0];
      kr1 = *(const bf16x8*)&k[kb2 + (size_t)(sr0 + 32) * EE + se0];
      const size_t vb2 = bh_vt + tn * 64;
      vr0 = *(const bf16x8*)&vt[vb2 + (size_t)sr0 * SS + se0];
      vr1 = *(const bf16x8*)&vt[vb2 + (size_t)(sr0 + 32) * SS + se0];
    }

    // PV(t-1): zero dependencies at barrier exit -> matrix pipe fills now
#pragma unroll
    for (int ct = 0; ct < 2; ++ct)
#pragma unroll
      for (int kb = 0; kb < 2; ++kb)
#pragma unroll
        for (int t16 = 0; t16 < 2; ++t16)
          accO[ct] = __builtin_amdgcn_mfma_f32_32x32x16_bf16(
              vfP[ct][kb * 2 + t16],
              __builtin_bit_cast(bf16x8, pwvP[kb][t16]), accO[ct], 0, 0, 0);

    // QK(t)
    f32x16 s[2];
#pragma unroll
    for (int kb = 0; kb < 2; ++kb) {
      f32x16 acc;
#pragma unroll
      for (int r = 0; r < 16; ++r) acc[r] = 0.f;
#pragma unroll
      for (int db = 0; db < 4; ++db) {
        bf16x8 ka = *(bf16x8*)&Ks[cur][(kb * 32 + lq) * 72 + db * 16 + h2 * 8];
        acc = __builtin_amdgcn_mfma_f32_32x32x16_bf16(ka, aq[db], acc, 0, 0, 0);
      }
      s[kb] = acc;
    }

    // exp(t)
    u32x4 pwvC[2][2];
#pragma unroll
    for (int kb = 0; kb < 2; ++kb)
#pragma unroll
      for (int t16 = 0; t16 < 2; ++t16)
#pragma unroll
        for (int j2 = 0; j2 < 4; ++j2) {
          float pa = __builtin_amdgcn_exp2f(s[kb][t16 * 8 + j2 * 2]);
          float pb = __builtin_amdgcn_exp2f(s[kb][t16 * 8 + j2 * 2 + 1]);
          lacc[kb] += pa + pb;
          pwvC[kb][t16][j2] = cvt_pk(pa, pb);
        }

    // capture V(t) frags to regs (PV(t) runs next iter)
#pragma unroll
    for (int ct = 0; ct < 2; ++ct)
#pragma unroll
      for (int kb = 0; kb < 2; ++kb)
#pragma unroll
        for (int t16 = 0; t16 < 2; ++t16)
          vfP[ct][kb * 2 + t16] = *(bf16x8*)&Vts[cur][(ct * 32 + lq) * 72 +
                                                      kb * 32 + t16 * 16 + h2 * 8];

    // stage tile tn into the other buffer
    {
      const int nxt = cur ^ 1;
      *(bf16x8*)&Ks[nxt][krow0 * 72 + se0] = kr0;
      *(bf16x8*)&Ks[nxt][(krow0 + 32) * 72 + se0] = kr1;
      *(bf16x8*)&Vts[nxt][sr0 * 72 + se0] = vr0;
      *(bf16x8*)&Vts[nxt][(sr0 + 32) * 72 + se0] = vr1;
    }
    __syncthreads();

#pragma unroll
    for (int kb = 0; kb < 2; ++kb)
#pragma unroll
      for (int t16 = 0; t16 < 2; ++t16) pwvP[kb][t16] = pwvC[kb][t16];
  }

  // epilogue: PV(31)
#pragma unroll
  for (int ct = 0; ct < 2; ++ct)
#pragma unroll
    for (int kb = 0; kb < 2; ++kb)
#pragma unroll
      for (int t16 = 0; t16 < 2; ++t16)
        accO[ct] = __builtin_amdgcn_mfma_f32_32x32x16_bf16(
            vfP[ct][kb * 2 + t16],
            __builtin_bit_cast(bf16x8, pwvP[kb][t16]), accO[ct], 0, 0, 0);

  // normalize: wave halves hold complementary key sums for the same q
  {
    float tsum = lacc[0] + lacc[1];
    tsum += __shfl_xor(tsum, 32, 64);
    float inv = 1.f / tsum;
    size_t row = (size_t)b * SS + q0 + lq;
#pragma unroll
    for (int ct = 0; ct < 2; ++ct)
#pragma unroll
      for (int rq = 0; rq < 4; ++rq) {
        uint2 pk;
        pk.x = cvt_pk(accO[ct][rq * 4 + 0] * inv, accO[ct][rq * 4 + 1] * inv);
        pk.y = cvt_pk(accO[ct][rq * 4 + 2] * inv, accO[ct][rq * 4 + 3] * inv);
        *(uint2*)&o[row * EE + h * DD + ct * 32 + rq * 8 + h2 * 4] = pk;
      }
  }
}

// ---------------------------------------------------------------------------
// Kernel 5: output projection, 128x128 tile, 2x2 waves of 64x64 sub-tiles:
// af 8 + wf 8 ds_reads feed 16 MFMAs (1.0 reads/MFMA). W staged
// sigma-permuted per 32-block; epilogue float4 stores. Grid (32,8) = 256.
// ---------------------------------------------------------------------------
__global__ __launch_bounds__(256) void out_proj_mfma(
    const ushort* __restrict__ a, const ushort* __restrict__ wo,
    const float* __restrict__ bias, float* __restrict__ y) {
  __shared__ __align__(16) ushort As[2][128 * 72];
  __shared__ __align__(16) ushort Ws[2][128 * 72];
  const int tid = threadIdx.x, l = tid & 63;
  const int wv = tid >> 6, wm = wv >> 1, wn = wv & 1;  // 2x2 wave grid
  const int lq = l & 31, h2 = l >> 5;
  const int m0 = blockIdx.x * 128, n0 = blockIdx.y * 128;
  const int sr = tid >> 3, se = (tid & 7) * 8;
  // sigma: swap bits 2,3 of the n-row index within its 32-block
  const int krow0 = (sr & 19) | ((sr & 4) << 1) | ((sr & 8) >> 1);

  f32x16 acc[2][2];  // [mb][nb]
#pragma unroll
  for (int mb = 0; mb < 2; ++mb)
#pragma unroll
    for (int nb = 0; nb < 2; ++nb)
#pragma unroll
      for (int r = 0; r < 16; ++r) acc[mb][nb][r] = 0.f;

  // prologue: stage k0=0 into buf 0
  {
#pragma unroll
    for (int j = 0; j < 4; ++j) {
      int r = sr + j * 32;
      *(bf16x8*)&As[0][r * 72 + se] = *(const bf16x8*)&a[(size_t)(m0 + r) * EE + se];
      *(bf16x8*)&Ws[0][(j * 32 + krow0) * 72 + se] =
          *(const bf16x8*)&wo[(size_t)(n0 + r) * EE + se];
    }
  }
  __syncthreads();

  for (int t = 0; t < 16; ++t) {
    const int cur = t & 1;
    bf16x8 Arg[4], Brg[4];
    if (t < 15) {
      const int k0 = (t + 1) * 64;
#pragma unroll
      for (int j = 0; j < 4; ++j) {
        int r = sr + j * 32;
        Arg[j] = *(const bf16x8*)&a[(size_t)(m0 + r) * EE + k0 + se];
        Brg[j] = *(const bf16x8*)&wo[(size_t)(n0 + r) * EE + k0 + se];
      }
    }

    // A frags: rows wm*64 + mb*32 + lq
    bf16x8 af[2][4];
#pragma unroll
    for (int mb = 0; mb < 2; ++mb)
#pragma unroll
      for (int db = 0; db < 4; ++db)
        af[mb][db] = *(bf16x8*)&As[cur][(wm * 64 + mb * 32 + lq) * 72 +
                                        db * 16 + h2 * 8];
    // W frags (A-operand, sigma'd rows) + MFMA
#pragma unroll
    for (int nb = 0; nb < 2; ++nb)
#pragma unroll
      for (int db = 0; db < 4; ++db) {
        bf16x8 wf = *(bf16x8*)&Ws[cur][(wn * 64 + nb * 32 + lq) * 72 +
                                       db * 16 + h2 * 8];
#pragma unroll
        for (int mb = 0; mb < 2; ++mb)
          acc[mb][nb] = __builtin_amdgcn_mfma_f32_32x32x16_bf16(
              wf, af[mb][db], acc[mb][nb], 0, 0, 0);
      }

    if (t < 15) {
      const int nxt = cur ^ 1;
#pragma unroll
      for (int j = 0; j < 4; ++j) {
        int r = sr + j * 32;
        *(bf16x8*)&As[nxt][r * 72 + se] = Arg[j];
        *(bf16x8*)&Ws[nxt][(j * 32 + krow0) * 72 + se] = Brg[j];
      }
    }
    __syncthreads();
  }

  // epilogue: lane owns m-row m0+wm*64+mb*32+lq;
  // regs t16*8+j -> n = n0 + wn*64 + nb*32 + t16*16 + h2*8 + j
#pragma unroll
  for (int mb = 0; mb < 2; ++mb) {
    const size_t row = (size_t)(m0 + wm * 64 + mb * 32 + lq) * EE;
#pragma unroll
    for (int nb = 0; nb < 2; ++nb)
#pragma unroll
      for (int t16 = 0; t16 < 2; ++t16) {
        const int nbase = n0 + wn * 64 + nb * 32 + t16 * 16 + h2 * 8;
        float4 bv0 = *(const float4*)&bias[nbase];
        float4 bv1 = *(const float4*)&bias[nbase + 4];
        float4 o0 = {acc[mb][nb][t16 * 8 + 0] + bv0.x,
                     acc[mb][nb][t16 * 8 + 1] + bv0.y,
                     acc[mb][nb][t16 * 8 + 2] + bv0.z,
                     acc[mb][nb][t16 * 8 + 3] + bv0.w};
        float4 o1 = {acc[mb][nb][t16 * 8 + 4] + bv1.x,
                     acc[mb][nb][t16 * 8 + 5] + bv1.y,
                     acc[mb][nb][t16 * 8 + 6] + bv1.z,
                     acc[mb][nb][t16 * 8 + 7] + bv1.w};
        *(float4*)&y[row + nbase] = o0;
        *(float4*)&y[row + nbase + 4] = o1;
      }
  }
}

// ---------------------------------------------------------------------------
extern "C" void kernel_launch(void* const* d_in, const int* in_sizes, int n_in,
                              void* d_out, int out_size, void* d_ws,
                              size_t ws_size, hipStream_t stream) {
  const float* x = (const float*)d_in[0];
  const float* Wq = (const float*)d_in[1];
  const float* Wk = (const float*)d_in[2];
  const float* Wv = (const float*)d_in[3];
  const float* Wo = (const float*)d_in[4];
  const float* bo = (const float*)d_in[5];
  float* out = (float*)d_out;

  const size_t per = (size_t)NROWS * 64;  // 4,194,304 elems
  ushort* qb = (ushort*)d_ws;                       //  8 MB
  ushort* kb = qb + per;                            //  8 MB
  ushort* vtb = kb + per;                           //  8 MB
  ushort* aob = vtb + per;                          //  8 MB
  ushort* wob = aob + per;                          //  2 MB

  qkv_mfma<<<dim3(32, 16, 2), 256, 0, stream>>>(x, Wq, Wk, Wv, Wo,
                                                qb, kb, vtb, wob);
  attn_mfma<<<512, 256, 0, stream>>>(qb, kb, vtb, aob);
  out_proj_mfma<<<dim3(32, 8), 256, 0, stream>>>(aob, wob, bo, out);
}